// Round 6
// baseline (56.009 us; speedup 1.0000x reference)
//
#include <hip/hip_runtime.h>

// Laplacian3D: LDS plane-ring (10 slots, 160 KiB) + per-thread register z-ring.
// Block = 1024 threads = full 64x64 (y,w) plane; each thread owns (y, w0..w0+3)
// and marches z. HBM -> LDS once via global_load_lds (prefetch distance 1,
// single barrier/step). z-taps come from a 9-deep float4 register ring fed by
// ONE ds_read/step; only y-taps (6) + w-taps (2) still read the center plane.
// Per-step LDS reads: 9 (was 15) -> LDS pipe ~1750 cyc/step < HBM ~2500 cyc.

#define NSLOT 10
#define PLANE 4096   // 64*64 floats = 16 KB
#define CHUNK 32

typedef float fx4 __attribute__((ext_vector_type(4)));

#define GLD(gsrc, ldst) __builtin_amdgcn_global_load_lds(                      \
    (const __attribute__((address_space(1))) unsigned int*)(gsrc),             \
    (__attribute__((address_space(3))) unsigned int*)(ldst), 16, 0, 0)

#define F4E(v, j) ((j) == 0 ? (v).x : (j) == 1 ? (v).y : (j) == 2 ? (v).z : (v).w)

__global__ __launch_bounds__(1024, 4) void lap3d_ring(
    const float* __restrict__ x, const float* __restrict__ p,
    float* __restrict__ out)
{
    __shared__ __align__(16) float lds[NSLOT][PLANE];   // 163840 B = 160 KiB

    const int tid   = threadIdx.x;
    const int bc    = blockIdx.x >> 1;        // b*64 + c
    const int chunk = blockIdx.x & 1;
    const int z0    = chunk * CHUNK;
    const int c     = bc & 63;

    const float* vol  = x   + (size_t)bc * (64 * PLANE);
    float*       ovol = out + (size_t)bc * (64 * PLANE);

    const int y     = tid >> 4;
    const int w0    = (tid & 15) << 2;
    const int foff  = tid << 2;               // y*64 + w0
    const int wbase = (tid >> 6) << 8;        // wave's float base in a plane

    const float k1  = 0.25f / (1.0f + __expf(-p[c]));
    const float k2  = 0.25f / (1.0f + __expf(-p[64 + c]));
    const float k4  = 0.25f / (1.0f + __expf(-p[128 + c]));
    const float km6 = -6.0f * (k1 + k2 + k4);

    // y-tap clamped offsets + masks (z-independent)
    const int dys[6] = {-4, -2, -1, 1, 2, 4};
    int yoff[6]; float ym[6];
#pragma unroll
    for (int k = 0; k < 6; ++k) {
        const int yy = y + dys[k];
        const bool v = (unsigned)yy < 64u;
        yoff[k] = (v ? yy : y) * 64 + w0;
        ym[k]   = v ? 1.0f : 0.0f;
    }
    // w-tap clamped offsets + masks (quad-aligned)
    const bool wmv = (w0 >= 4), wpv = (w0 <= 56);
    const int   wmoff = wmv ? foff - 4 : foff;
    const int   wpoff = wpv ? foff + 4 : foff;
    const float wmm = wmv ? 1.0f : 0.0f, wpm = wpv ? 1.0f : 0.0f;

    // prologue: planes z0-4 .. z0+4 into slots q%10
#pragma unroll
    for (int i = 0; i < 9; ++i) {
        const int q = z0 - 4 + i;
        if (q >= 0 && q < 64)                 // uniform
            GLD(vol + (size_t)q * PLANE + foff, &lds[q % NSLOT][wbase]);
    }
    __syncthreads();

    const float4 zero = make_float4(0.f, 0.f, 0.f, 0.f);

    // register z-ring init: r1..r8 <- planes z0-4 .. z0+3 (from LDS)
    float4 r0 = zero, r1, r2, r3, r4, r5, r6, r7, r8;
    {
        float4* rr[8] = {&r1, &r2, &r3, &r4, &r5, &r6, &r7, &r8};
#pragma unroll
        for (int i = 0; i < 8; ++i) {
            const int q = z0 - 4 + i;
            *rr[i] = (q >= 0) ? *(const float4*)(&lds[q % NSLOT][foff]) : zero;
        }
    }

    // incremental slot counters (no % in the loop)
    int sc = z0 % NSLOT;                      // slot of plane z
    int sf = (z0 + 4) % NSLOT;                // slot of plane z+4 (ring fill)
    int sp = (z0 + 5) % NSLOT;                // slot of plane z+5 (prefetch)

    for (int iz = 0; iz < CHUNK; ++iz) {
        const int z = z0 + iz;

        // prefetch plane z+5 (slot disjoint from planes z..z+4 still in use;
        // its previous occupant z-5 was last read at step z-5)
        if (z + 5 < 64 && iz < CHUNK - 1)     // uniform
            GLD(vol + (size_t)(z + 5) * PLANE + foff, &lds[sp][wbase]);

        // ring shift + fill (after fill: r_i holds plane z-4+i at foff)
        r0 = r1; r1 = r2; r2 = r3; r3 = r4; r4 = r5; r5 = r6; r6 = r7; r7 = r8;
        r8 = (z + 4 < 64) ? *(const float4*)(&lds[sf][foff]) : zero;

        const float* plz = lds[sc];

        // w-window from LDS (center from register r4)
        const float4 wm = *(const float4*)(plz + wmoff);
        const float4 wp = *(const float4*)(plz + wpoff);

        // y taps (clamped addresses; masked in the FMA)
        const float4 ym4t = *(const float4*)(plz + yoff[0]);
        const float4 ym2t = *(const float4*)(plz + yoff[1]);
        const float4 ym1t = *(const float4*)(plz + yoff[2]);
        const float4 yp1t = *(const float4*)(plz + yoff[3]);
        const float4 yp2t = *(const float4*)(plz + yoff[4]);
        const float4 yp4t = *(const float4*)(plz + yoff[5]);

        const float win[12] = {wm.x * wmm, wm.y * wmm, wm.z * wmm, wm.w * wmm,
                               r4.x, r4.y, r4.z, r4.w,
                               wp.x * wpm, wp.y * wpm, wp.z * wpm, wp.w * wpm};

        fx4 o;
#pragma unroll
        for (int j = 0; j < 4; ++j) {
            const float s1 = F4E(r3, j) + F4E(r5, j) + win[3 + j] + win[5 + j]
                           + ym[2] * F4E(ym1t, j) + ym[3] * F4E(yp1t, j);
            const float s2 = F4E(r2, j) + F4E(r6, j) + win[2 + j] + win[6 + j]
                           + ym[1] * F4E(ym2t, j) + ym[4] * F4E(yp2t, j);
            const float s4 = F4E(r0, j) + F4E(r8, j) + win[j] + win[8 + j]
                           + ym[0] * F4E(ym4t, j) + ym[5] * F4E(yp4t, j);
            o[j] = km6 * win[4 + j] + k1 * s1 + k2 * s2 + k4 * s4;
        }
        __builtin_nontemporal_store(o, (fx4*)(ovol + (size_t)z * PLANE + foff));

        __syncthreads();   // drains prefetch (hidden under compute); frees
                           // slot (z-4) for the next step's prefetch

        sc = (sc + 1 == NSLOT) ? 0 : sc + 1;
        sf = (sf + 1 == NSLOT) ? 0 : sf + 1;
        sp = (sp + 1 == NSLOT) ? 0 : sp + 1;
    }
}

extern "C" void kernel_launch(void* const* d_in, const int* in_sizes, int n_in,
                              void* d_out, int out_size, void* d_ws, size_t ws_size,
                              hipStream_t stream) {
    const float* x = (const float*)d_in[0];
    const float* p = (const float*)d_in[1];
    float* out = (float*)d_out;
    lap3d_ring<<<256, 1024, 0, stream>>>(x, p, out);
}